// Round 10
// baseline (194.742 us; speedup 1.0000x reference)
//
#include <hip/hip_runtime.h>

constexpr int N_ = 4096, C_ = 32, CN_ = 64, M_ = 64;
constexpr int TPB = 1024;             // fps block: 16 waves, 4/SIMD
constexpr int RPT = 3, LPT = 1;       // reg / LDS points per thread
constexpr int NREG = RPT * TPB;       // 3072
constexpr int NLDS = N_ - NREG;       // 1024
constexpr int NWAVES = TPB / 64;      // 16
constexpr int NTPB = 256;             // norms block
constexpr int NCHUNK = N_ / NTPB;     // 16

__device__ __forceinline__ unsigned long long shfl_xor_u64(unsigned long long v, int m) {
  unsigned lo = __shfl_xor((unsigned)v, m);
  unsigned hi = __shfl_xor((unsigned)(v >> 32), m);
  return ((unsigned long long)hi << 32) | lo;
}

// monotone f32 -> u32 map (total order preserved incl. negatives)
__device__ __forceinline__ unsigned fmap(float v) {
  unsigned u = __float_as_uint(v);
  u ^= (unsigned)((int)u >> 31) | 0x80000000u;
  return u;
}

// force a wave-uniform float into an SGPR
__device__ __forceinline__ float rfl(float v) {
  return __uint_as_float(__builtin_amdgcn_readfirstlane(__float_as_uint(v)));
}

// ---------------- kernel 0: per-point z = G·x (f64 accum) + norms + Σx partials ----------------
// blk = (b*3+r)*16 + chunk ; r=0: G=I, r=1: G=Wk^T Wk, r=2: G=Wv^T Wv
__global__ __attribute__((amdgpu_flat_work_group_size(NTPB, NTPB),
                          amdgpu_waves_per_eu(1, 4)))
void norms_kernel(
    const float* __restrict__ ev, const float* __restrict__ Wk,
    const float* __restrict__ Wv, float* __restrict__ nrm_all,
    float* __restrict__ zall, float* __restrict__ partials) {
  int blk = blockIdx.x;
  int chunk = blk & (NCHUNK - 1), br = blk >> 4;
  int r = br % 3, b = br / 3;
  int t = threadIdx.x;
  __shared__ float G[C_][C_ + 1];
  const float* W = (r == 1) ? Wk : Wv;
  for (int e = t; e < C_ * C_; e += NTPB) {
    int a = e >> 5, d = e & 31;
    float g;
    if (r == 0) {
      g = (a == d) ? 1.f : 0.f;
    } else {
      double acc = 0.0;
      for (int q = 0; q < CN_; ++q)
        acc += (double)W[q * C_ + a] * (double)W[q * C_ + d];
      g = (float)acc;
    }
    G[a][d] = g;
  }
  __syncthreads();
  int p = chunk * NTPB + t;
  const float4* row = (const float4*)(ev + ((size_t)b * N_ + p) * C_);
  float x[C_];
#pragma unroll
  for (int q = 0; q < C_ / 4; ++q) {
    float4 v = row[q];
    x[q * 4 + 0] = v.x; x[q * 4 + 1] = v.y; x[q * 4 + 2] = v.z; x[q * 4 + 3] = v.w;
  }
  double n = 0.0;
  float z[C_];
#pragma unroll
  for (int a = 0; a < C_; ++a) {
    double ta = 0.0;
#pragma unroll
    for (int d = 0; d < C_; ++d) ta += (double)G[a][d] * (double)x[d];
    z[a] = (float)ta;
    n += ta * (double)x[a];
  }
  nrm_all[(size_t)br * N_ + p] = (float)n;
  float4* zrow = (float4*)(zall + ((size_t)br * N_ + p) * C_);
#pragma unroll
  for (int q = 0; q < C_ / 4; ++q)
    zrow[q] = make_float4(z[q * 4 + 0], z[q * 4 + 1], z[q * 4 + 2], z[q * 4 + 3]);

  if (r == 0) {   // deterministic per-chunk Σx partials (no atomics)
    __shared__ float msum[NTPB / 64][C_];
#pragma unroll
    for (int d = 0; d < C_; ++d) {
      float s = x[d];
#pragma unroll
      for (int off = 32; off; off >>= 1) s += __shfl_xor(s, off);
      if ((t & 63) == 0) msum[t >> 6][d] = s;
    }
    __syncthreads();
    if (t < C_)
      partials[((size_t)b * NCHUNK + chunk) * C_ + t] =
          msum[0][t] + msum[1][t] + msum[2][t] + msum[3][t];
  }
}

// ---------------- kernel 1: FPS — one block per (batch,run), z-metric ----------------
// d(i, sel) = n_i - 2 * z_i · x_sel + n_sel    (G symmetric: x_i·G·c = z_i·c)
// amdgpu_waves_per_eu(4,4): VGPR budget = 512/4 = 128 exactly.
// (launch_bounds min-waves alone let the allocator target 8/EU -> 64 VGPR -> spill.)
__global__ __attribute__((amdgpu_flat_work_group_size(TPB, TPB),
                          amdgpu_waves_per_eu(4, 4)))
void fps_kernel(
    const float* __restrict__ ev, const float* __restrict__ nrm_all,
    const float* __restrict__ zall, const float* __restrict__ partials,
    int* __restrict__ idx_ws) {
  const int t = threadIdx.x;
  const int blk = blockIdx.x;          // b*3 + r
  const int b = blk / 3;
  const float* evb = ev + (size_t)b * N_ * C_;
  const float* nrm = nrm_all + (size_t)blk * N_;
  const float4* zb4 = (const float4*)(zall + (size_t)blk * N_ * C_);

  __shared__ float LP[C_ / 4][NLDS][4];   // [q][col][4] — conflict-free b128 (128 KB)
  __shared__ float cf0[C_];               // barycenter (round 0 only)
  __shared__ unsigned long long redK[2][NWAVES];

  float z[RPT][C_], pn[RPT], dmin[RPT];
  float nl, dminL;

  // ---- load reg z-points ----
#pragma unroll
  for (int j = 0; j < RPT; ++j) {
    int p = j * TPB + t;
#pragma unroll
    for (int q = 0; q < C_ / 4; ++q) {
      float4 v = zb4[(size_t)p * 8 + q];
      z[j][q * 4 + 0] = v.x; z[j][q * 4 + 1] = v.y;
      z[j][q * 4 + 2] = v.z; z[j][q * 4 + 3] = v.w;
    }
    pn[j] = nrm[p];
    dmin[j] = 1e10f;
  }
  // ---- stage LDS z-point (1 per thread), [q][col] layout ----
  {
    int p = NREG + t;
#pragma unroll
    for (int q = 0; q < C_ / 4; ++q) {
      float4 v = zb4[(size_t)p * 8 + q];
      *(float4*)&LP[q][t][0] = v;
    }
    nl = nrm[p];
    dminL = 1e10f;
  }
  // ---- barycenter from partials (deterministic) ----
  if (t < C_) {
    float s = 0.f;
#pragma unroll
    for (int c = 0; c < NCHUNK; ++c) s += partials[((size_t)b * NCHUNK + c) * C_ + t];
    cf0[t] = s * (1.f / (float)N_);
  }
  __syncthreads();   // LP + cf0 ready

  // cs[] is wave-uniform (SGPR-resident): FMAs take 1 SGPR operand, no VGPR cost.
  // returns wave-reduced packed key: (fmap(best_v) << 12) | (4095 - best_idx)
  auto eval = [&](const float (&cs)[C_], float curN,
                  bool update) -> unsigned long long {
    float a0 = 0.f, a1 = 0.f, a2 = 0.f, aL = 0.f;
#pragma unroll
    for (int q = 0; q < C_ / 4; ++q) {
      float4 l = *(const float4*)&LP[q][t][0];
#pragma unroll
      for (int e = 0; e < 4; ++e) {
        float c = cs[q * 4 + e];
        a0 = fmaf(z[0][q * 4 + e], c, a0);
        a1 = fmaf(z[1][q * 4 + e], c, a1);
        a2 = fmaf(z[2][q * 4 + e], c, a2);
        aL = fmaf((&l.x)[e], c, aL);
      }
    }
    float acc[RPT] = {a0, a1, a2};
    float bv = -3e38f; int bi = 0;
#pragma unroll
    for (int j = 0; j < RPT; ++j) {
      float d = fmaf(-2.f, acc[j], pn[j]) + curN;
      float v;
      if (update) { dmin[j] = fminf(dmin[j], d); v = dmin[j]; }
      else v = d;
      if (v > bv) { bv = v; bi = j * TPB + t; }   // strict > keeps lowest index
    }
    {
      float d = fmaf(-2.f, aL, nl) + curN;
      float v;
      if (update) { dminL = fminf(dminL, d); v = dminL; }
      else v = d;
      if (v > bv) { bv = v; bi = NREG + t; }
    }
    unsigned long long k =
        ((unsigned long long)fmap(bv) << 12) | (unsigned)(4095 - bi);
#pragma unroll
    for (int off = 1; off < 64; off <<= 1) {
      unsigned long long ko = shfl_xor_u64(k, off);
      if (ko > k) k = ko;
    }
    return k;
  };

  // ---- round 0: barycenter (additive shift irrelevant for argmax; no dmin update) ----
  {
    float cs[C_];
#pragma unroll
    for (int d = 0; d < C_; ++d) cs[d] = rfl(cf0[d]);
    unsigned long long k = eval(cs, 0.f, false);
    if ((t & 63) == 0) redK[0][t >> 6] = k;
  }
  __syncthreads();

  // ---- main loop: 1 barrier/iter; cross-wave reduce = 1 ds_read + 4 shfl stages
  // (NOT a 16-entry per-thread scan: that was 256 LDS instrs/CU/iter) ----
  for (int it = 0; it < M_; ++it) {
    int rb = it & 1;
    unsigned long long k = redK[rb][t & (NWAVES - 1)];
#pragma unroll
    for (int off = 1; off < NWAVES; off <<= 1) {
      unsigned long long ko = shfl_xor_u64(k, off);
      if (ko > k) k = ko;
    }
    int jsel = 4095 - (int)(k & 4095ull);
    if (t == 0) idx_ws[blk * M_ + it] = jsel;
    // owner kills its dmin slot (never re-select) — static indices only
    if (jsel < NREG) {
      if ((jsel & (TPB - 1)) == t) {
        int j = jsel >> 10;
        if (j == 0) dmin[0] = -3e38f;
        else if (j == 1) dmin[1] = -3e38f;
        else dmin[2] = -3e38f;
      }
    } else {
      if (jsel - NREG == t) dminL = -3e38f;
    }
    if (it == M_ - 1) break;
    // uniform index -> SGPR-resident centroid + norm (scalar loads)
    int jsu = __builtin_amdgcn_readfirstlane(jsel);
    float curN = rfl(nrm[jsu]);
    const float* cf = evb + (size_t)jsu * C_;
    float cs[C_];
#pragma unroll
    for (int d = 0; d < C_; ++d) cs[d] = rfl(cf[d]);
    unsigned long long kk = eval(cs, curN, true);
    if ((t & 63) == 0) redK[rb ^ 1][t >> 6] = kk;
    __syncthreads();
  }
}

// ---------------- kernel 2: finalize (256 threads per batch) ----------------
// fps() returns selections in ASCENDING ORIGINAL-INDEX order (masked_select);
// rank-sort each run's indices before zipping along m (pairing matters).
// PRJ[0]=pe (ev-run pts @ Wpe), PRJ[1]=km (k-run pts @ Wk), PRJ[2]=vm (v-run @ Wv).
__global__ __launch_bounds__(256, 1) void finalize_kernel(
    const float* __restrict__ ev, const float* __restrict__ Wk,
    const float* __restrict__ Wv, const float* __restrict__ Wpe,
    const float* __restrict__ Wsa1, const float* __restrict__ Wsa2,
    const int* __restrict__ idx_ws, const float* __restrict__ partials,
    float* __restrict__ outvec_ws) {
  const int b = blockIdx.x;
  const int t = threadIdx.x;           // 256 threads = 4 waves
  const float* evb = ev + (size_t)b * N_ * C_;

  __shared__ float Wl[3][CN_][C_];        // 24 KB: Wpe, Wk, Wv
  __shared__ float W1l[CN_];
  __shared__ float W2l[C_][CN_ + 1];      // padded: conflict-free per-lane rows
  __shared__ int   lidx[3][M_], sidx[3][M_];
  __shared__ float XP[3][M_][C_];         // 24 KB selected rows
  __shared__ float PRJ[3][M_][CN_ + 1];   // padded
  __shared__ float sumx[C_], Pl[CN_], sl[M_], TP[4][CN_];

  // ---- stage weights ----
  {
    const float* Ws[3] = {Wpe, Wk, Wv};
#pragma unroll
    for (int r = 0; r < 3; ++r)
      for (int i = t; i < CN_ * C_ / 4; i += 256)
        ((float4*)&Wl[r][0][0])[i] = ((const float4*)Ws[r])[i];
    if (t < CN_) W1l[t] = Wsa1[t];
    for (int i = t; i < C_ * CN_; i += 256)
      W2l[i >> 6][i & 63] = Wsa2[i];      // scalar (padded dest not f4-aligned)
  }
  if (t < 192) {
    int r = t >> 6, mm = t & 63;
    lidx[r][mm] = idx_ws[(b * 3 + r) * M_ + mm];
  }
  if (t < C_) {
    float s = 0.f;
#pragma unroll
    for (int c = 0; c < NCHUNK; ++c) s += partials[((size_t)b * NCHUNK + c) * C_ + t];
    sumx[t] = s;
  }
  __syncthreads();
  if (t < 192) {       // parallel rank-sort: 3 runs × 64 slots
    int r = t >> 6, mm = t & 63;
    int my = lidx[r][mm];
    int rank = 0;
#pragma unroll
    for (int j = 0; j < M_; ++j)
      rank += (lidx[r][j] < my) || (lidx[r][j] == my && j < mm);
    sidx[r][rank] = my;
  }
  __syncthreads();
  // ---- stage selected rows: 192 rows × 8 quads ----
  for (int g = t; g < 3 * M_ * 8; g += 256) {
    int row = g >> 3, q = g & 7;
    int r = row >> 6, m = row & 63;
    int pi = sidx[r][m];
    *(float4*)&XP[r][m][q * 4] = ((const float4*)(evb + (size_t)pi * C_))[q];
  }
  __syncthreads();
  // ---- projections: wave r handles run r (lane = cn, W row in regs, x broadcast) ----
  {
    int w = t >> 6, cn = t & 63;
    if (w < 3) {
      float wr[C_];
#pragma unroll
      for (int q = 0; q < C_ / 4; ++q) {
        float4 v = *(const float4*)&Wl[w][cn][q * 4];
        wr[q * 4 + 0] = v.x; wr[q * 4 + 1] = v.y;
        wr[q * 4 + 2] = v.z; wr[q * 4 + 3] = v.w;
      }
      for (int m = 0; m < M_; ++m) {
        float a = 0.f;
#pragma unroll
        for (int q = 0; q < C_ / 4; ++q) {
          float4 x = *(const float4*)&XP[w][m][q * 4];   // wave-broadcast read
          a = fmaf(x.x, wr[q * 4 + 0], a);
          a = fmaf(x.y, wr[q * 4 + 1], a);
          a = fmaf(x.z, wr[q * 4 + 2], a);
          a = fmaf(x.w, wr[q * 4 + 3], a);
        }
        PRJ[w][m][cn] = a;
      }
    } else {
      // Pl[cn] = (Σ_n ev) @ Wpe^T
      float a = 0.f;
#pragma unroll
      for (int c = 0; c < C_; ++c) a = fmaf(sumx[c], Wl[0][cn][c], a);
      Pl[cn] = a;
    }
  }
  __syncthreads();
  // ---- logits + softmax: wave 0, lane m ----
  if (t < 64) {
    float cm = 0.f;
#pragma unroll 8
    for (int cn = 0; cn < CN_; ++cn)
      cm = fmaf(PRJ[1][t][cn] + PRJ[0][t][cn], W1l[cn], cm);
    float lg = -cm;
    float mx = lg;
#pragma unroll
    for (int off = 32; off; off >>= 1) mx = fmaxf(mx, __shfl_xor(mx, off));
    float e = expf(lg - mx);
    float ssum = e;
#pragma unroll
    for (int off = 32; off; off >>= 1) ssum += __shfl_xor(ssum, off);
    sl[t] = e / ssum;
  }
  __syncthreads();
  // ---- tvec partials: thread (cn = t&63, quarter h = t>>6) ----
  {
    int cn = t & 63, h = t >> 6;
    float a = 0.f;
#pragma unroll
    for (int i = 0; i < 16; ++i) {
      int mm = h * 16 + i;
      a = fmaf(sl[mm],
               fmaf((float)N_, PRJ[2][mm][cn], Pl[cn]) - (float)N_ * PRJ[0][mm][cn],
               a);
    }
    TP[h][cn] = a;
  }
  __syncthreads();
  if (t < C_) {
    float o = 0.f;
#pragma unroll 8
    for (int cn = 0; cn < CN_; ++cn) {
      float tv = TP[0][cn] + TP[1][cn] + TP[2][cn] + TP[3][cn];
      o = fmaf(tv, W2l[t][cn], o);
    }
    outvec_ws[b * C_ + t] = o;
  }
}

// ---------------- kernel 3: broadcast out[b][n][:] = outvec[b][:] ----------------
__global__ void bcast_kernel(const float* __restrict__ outvec_ws,
                             float4* __restrict__ out) {
  int i = blockIdx.x * 256 + threadIdx.x;   // < 4*4096*8
  int b = i >> 15;
  int j = i & 7;
  const float4* ov = (const float4*)outvec_ws;
  out[i] = ov[b * 8 + j];
}

extern "C" void kernel_launch(void* const* d_in, const int* in_sizes, int n_in,
                              void* d_out, int out_size, void* d_ws, size_t ws_size,
                              hipStream_t stream) {
  const float* ev   = (const float*)d_in[0];
  // d_in[1] = W_qs: provably unused (a_n cancels in softmax over m)
  const float* Wk   = (const float*)d_in[2];
  const float* Wv   = (const float*)d_in[3];
  const float* Wpe  = (const float*)d_in[4];
  const float* Wsa1 = (const float*)d_in[5];
  const float* Wsa2 = (const float*)d_in[6];
  float* out = (float*)d_out;

  char* ws = (char*)d_ws;
  int*   idx    = (int*)ws;                     // 12*64*4        = 3072 B
  float* parts  = (float*)(ws + 3072);          // 4*16*32*4      = 8192 B
  float* outvec = (float*)(ws + 11264);         // 4*32*4         = 512 B
  float* nrm    = (float*)(ws + 11776);         // 12*4096*4      = 196608 B
  float* zall   = (float*)(ws + 208384);        // 12*4096*32*4   = 6291456 B

  norms_kernel   <<<dim3(192), dim3(NTPB), 0, stream>>>(ev, Wk, Wv, nrm, zall, parts);
  fps_kernel     <<<dim3(12),  dim3(TPB),  0, stream>>>(ev, nrm, zall, parts, idx);
  finalize_kernel<<<dim3(4),   dim3(256),  0, stream>>>(ev, Wk, Wv, Wpe, Wsa1, Wsa2,
                                                        idx, parts, outvec);
  bcast_kernel   <<<dim3(512), dim3(256),  0, stream>>>(outvec, (float4*)out);
}

// Round 11
// 163.777 us; speedup vs baseline: 1.1891x; 1.1891x over previous
//
#include <hip/hip_runtime.h>

constexpr int N_ = 4096, C_ = 32, CN_ = 64, M_ = 64;
constexpr int TPB = 1024;             // fps block: 16 waves, 4/SIMD
constexpr int RPT = 3, LPT = 1;       // reg / LDS points per thread
constexpr int NREG = RPT * TPB;       // 3072
constexpr int NLDS = N_ - NREG;       // 1024
constexpr int NWAVES = TPB / 64;      // 16
constexpr int NTPB = 256;             // norms block
constexpr int NCHUNK = N_ / NTPB;     // 16

// monotone f32 -> u32 map (total order preserved incl. negatives)
__device__ __forceinline__ unsigned fmap(float v) {
  unsigned u = __float_as_uint(v);
  u ^= (unsigned)((int)u >> 31) | 0x80000000u;
  return u;
}

// force a wave-uniform float into an SGPR
__device__ __forceinline__ float rfl(float v) {
  return __uint_as_float(__builtin_amdgcn_readfirstlane(__float_as_uint(v)));
}

// one DPP max-combine stage on a packed u64 key (VALU pipe — no LDS traffic).
// Lanes excluded by ROW_MASK / without a valid source keep their own value.
template <int CTRL, int RM>
__device__ __forceinline__ unsigned long long kmax_dpp(unsigned long long k) {
  int lo = (int)(unsigned)k, hi = (int)(unsigned)(k >> 32);
  int plo = __builtin_amdgcn_update_dpp(lo, lo, CTRL, RM, 0xf, false);
  int phi = __builtin_amdgcn_update_dpp(hi, hi, CTRL, RM, 0xf, false);
  unsigned long long p =
      ((unsigned long long)(unsigned)phi << 32) | (unsigned)plo;
  return p > k ? p : k;
}

// full-wave max of packed key via row_shr prefix + row broadcasts; lane 63 holds it.
__device__ __forceinline__ unsigned long long wave_kmax(unsigned long long k) {
  k = kmax_dpp<0x111, 0xF>(k);   // row_shr:1
  k = kmax_dpp<0x112, 0xF>(k);   // row_shr:2
  k = kmax_dpp<0x114, 0xF>(k);   // row_shr:4
  k = kmax_dpp<0x118, 0xF>(k);   // row_shr:8
  k = kmax_dpp<0x142, 0xA>(k);   // row_bcast:15 -> rows 1,3
  k = kmax_dpp<0x143, 0xC>(k);   // row_bcast:31 -> rows 2,3
  return k;
}

// ---------------- kernel 0: per-point z = G·x (f64 accum) + norms + Σx partials ----------------
// blk = (b*3+r)*16 + chunk ; r=0: G=I, r=1: G=Wk^T Wk, r=2: G=Wv^T Wv
__global__ __attribute__((amdgpu_flat_work_group_size(NTPB, NTPB),
                          amdgpu_waves_per_eu(1, 4)))
void norms_kernel(
    const float* __restrict__ ev, const float* __restrict__ Wk,
    const float* __restrict__ Wv, float* __restrict__ nrm_all,
    float* __restrict__ zall, float* __restrict__ partials) {
  int blk = blockIdx.x;
  int chunk = blk & (NCHUNK - 1), br = blk >> 4;
  int r = br % 3, b = br / 3;
  int t = threadIdx.x;
  __shared__ float G[C_][C_ + 1];
  const float* W = (r == 1) ? Wk : Wv;
  for (int e = t; e < C_ * C_; e += NTPB) {
    int a = e >> 5, d = e & 31;
    float g;
    if (r == 0) {
      g = (a == d) ? 1.f : 0.f;
    } else {
      double acc = 0.0;
      for (int q = 0; q < CN_; ++q)
        acc += (double)W[q * C_ + a] * (double)W[q * C_ + d];
      g = (float)acc;
    }
    G[a][d] = g;
  }
  __syncthreads();
  int p = chunk * NTPB + t;
  const float4* row = (const float4*)(ev + ((size_t)b * N_ + p) * C_);
  float x[C_];
#pragma unroll
  for (int q = 0; q < C_ / 4; ++q) {
    float4 v = row[q];
    x[q * 4 + 0] = v.x; x[q * 4 + 1] = v.y; x[q * 4 + 2] = v.z; x[q * 4 + 3] = v.w;
  }
  double n = 0.0;
  float z[C_];
#pragma unroll
  for (int a = 0; a < C_; ++a) {
    double ta = 0.0;
#pragma unroll
    for (int d = 0; d < C_; ++d) ta += (double)G[a][d] * (double)x[d];
    z[a] = (float)ta;
    n += ta * (double)x[a];
  }
  nrm_all[(size_t)br * N_ + p] = (float)n;
  float4* zrow = (float4*)(zall + ((size_t)br * N_ + p) * C_);
#pragma unroll
  for (int q = 0; q < C_ / 4; ++q)
    zrow[q] = make_float4(z[q * 4 + 0], z[q * 4 + 1], z[q * 4 + 2], z[q * 4 + 3]);

  if (r == 0) {   // deterministic per-chunk Σx partials (no atomics)
    __shared__ float msum[NTPB / 64][C_];
#pragma unroll
    for (int d = 0; d < C_; ++d) {
      float s = x[d];
#pragma unroll
      for (int off = 32; off; off >>= 1) s += __shfl_xor(s, off);
      if ((t & 63) == 0) msum[t >> 6][d] = s;
    }
    __syncthreads();
    if (t < C_)
      partials[((size_t)b * NCHUNK + chunk) * C_ + t] =
          msum[0][t] + msum[1][t] + msum[2][t] + msum[3][t];
  }
}

// ---------------- kernel 1: FPS — one block per (batch,run), z-metric ----------------
// d(i, sel) = n_i - 2 * z_i · x_sel + n_sel    (G symmetric: x_i·G·c = z_i·c)
__global__ __attribute__((amdgpu_flat_work_group_size(TPB, TPB),
                          amdgpu_waves_per_eu(4, 4)))
void fps_kernel(
    const float* __restrict__ ev, const float* __restrict__ nrm_all,
    const float* __restrict__ zall, const float* __restrict__ partials,
    int* __restrict__ idx_ws) {
  const int t = threadIdx.x;
  const int blk = blockIdx.x;          // b*3 + r
  const int b = blk / 3;
  const float* evb = ev + (size_t)b * N_ * C_;
  const float* nrm = nrm_all + (size_t)blk * N_;
  const float4* zb4 = (const float4*)(zall + (size_t)blk * N_ * C_);

  __shared__ float LP[C_ / 4][NLDS][4];   // [q][col][4] — conflict-free b128 (128 KB)
  __shared__ float cf0[C_];               // barycenter (round 0 only)
  __shared__ unsigned long long redK[2][NWAVES];

  float z[RPT][C_], pn[RPT], dmin[RPT];
  float nl, dminL;

  // ---- load reg z-points ----
#pragma unroll
  for (int j = 0; j < RPT; ++j) {
    int p = j * TPB + t;
#pragma unroll
    for (int q = 0; q < C_ / 4; ++q) {
      float4 v = zb4[(size_t)p * 8 + q];
      z[j][q * 4 + 0] = v.x; z[j][q * 4 + 1] = v.y;
      z[j][q * 4 + 2] = v.z; z[j][q * 4 + 3] = v.w;
    }
    pn[j] = nrm[p];
    dmin[j] = 1e10f;
  }
  // ---- stage LDS z-point (1 per thread), [q][col] layout ----
  {
    int p = NREG + t;
#pragma unroll
    for (int q = 0; q < C_ / 4; ++q) {
      float4 v = zb4[(size_t)p * 8 + q];
      *(float4*)&LP[q][t][0] = v;
    }
    nl = nrm[p];
    dminL = 1e10f;
  }
  // ---- barycenter from partials (deterministic) ----
  if (t < C_) {
    float s = 0.f;
#pragma unroll
    for (int c = 0; c < NCHUNK; ++c) s += partials[((size_t)b * NCHUNK + c) * C_ + t];
    cf0[t] = s * (1.f / (float)N_);
  }
  __syncthreads();   // LP + cf0 ready

  // cs[] is wave-uniform (SGPR-resident). Returns wave-reduced packed key in
  // lane 63: (fmap(best_v) << 12) | (4095 - best_idx). DPP reduce: no LDS ops.
  auto eval = [&](const float (&cs)[C_], float curN,
                  bool update) -> unsigned long long {
    float a0 = 0.f, a1 = 0.f, a2 = 0.f, aL = 0.f;
#pragma unroll
    for (int q = 0; q < C_ / 4; ++q) {
      float4 l = *(const float4*)&LP[q][t][0];
#pragma unroll
      for (int e = 0; e < 4; ++e) {
        float c = cs[q * 4 + e];
        a0 = fmaf(z[0][q * 4 + e], c, a0);
        a1 = fmaf(z[1][q * 4 + e], c, a1);
        a2 = fmaf(z[2][q * 4 + e], c, a2);
        aL = fmaf((&l.x)[e], c, aL);
      }
    }
    float acc[RPT] = {a0, a1, a2};
    float bv = -3e38f; int bi = 0;
#pragma unroll
    for (int j = 0; j < RPT; ++j) {
      float d = fmaf(-2.f, acc[j], pn[j]) + curN;
      float v;
      if (update) { dmin[j] = fminf(dmin[j], d); v = dmin[j]; }
      else v = d;
      if (v > bv) { bv = v; bi = j * TPB + t; }   // strict > keeps lowest index
    }
    {
      float d = fmaf(-2.f, aL, nl) + curN;
      float v;
      if (update) { dminL = fminf(dminL, d); v = dminL; }
      else v = d;
      if (v > bv) { bv = v; bi = NREG + t; }
    }
    unsigned long long k =
        ((unsigned long long)fmap(bv) << 12) | (unsigned)(4095 - bi);
    return wave_kmax(k);
  };

  // ---- round 0: barycenter (additive shift irrelevant for argmax; no dmin update) ----
  {
    float cs[C_];
#pragma unroll
    for (int d = 0; d < C_; ++d) cs[d] = rfl(cf0[d]);
    unsigned long long k = eval(cs, 0.f, false);
    if ((t & 63) == 63) redK[0][t >> 6] = k;
  }
  __syncthreads();

  // ---- main loop: 1 barrier/iter; cross-wave reduce = 1 ds_read_b64 +
  // 4 DPP stages within row-16 + v_readlane -> SGPR-uniform jsel ----
  for (int it = 0; it < M_; ++it) {
    int rb = it & 1;
    unsigned long long k = redK[rb][t & (NWAVES - 1)];
    k = kmax_dpp<0x111, 0xF>(k);
    k = kmax_dpp<0x112, 0xF>(k);
    k = kmax_dpp<0x114, 0xF>(k);
    k = kmax_dpp<0x118, 0xF>(k);
    // lane 15 of every row-16 holds the max over all 16 wave entries
    unsigned klo = (unsigned)__builtin_amdgcn_readlane((int)(unsigned)k, 15);
    int jsel = 4095 - (int)(klo & 4095u);          // SGPR-uniform
    if (t == 0) idx_ws[blk * M_ + it] = jsel;
    // owner kills its dmin slot (never re-select) — static indices only
    if (jsel < NREG) {
      if ((jsel & (TPB - 1)) == t) {
        int j = jsel >> 10;
        if (j == 0) dmin[0] = -3e38f;
        else if (j == 1) dmin[1] = -3e38f;
        else dmin[2] = -3e38f;
      }
    } else {
      if (jsel - NREG == t) dminL = -3e38f;
    }
    if (it == M_ - 1) break;
    // uniform index -> SGPR-resident centroid + norm (scalar loads)
    float curN = rfl(nrm[jsel]);
    const float* cf = evb + (size_t)jsel * C_;
    float cs[C_];
#pragma unroll
    for (int d = 0; d < C_; ++d) cs[d] = rfl(cf[d]);
    unsigned long long kk = eval(cs, curN, true);
    if ((t & 63) == 63) redK[rb ^ 1][t >> 6] = kk;
    __syncthreads();
  }
}

// ---------------- kernel 2: finalize (256 threads per batch) ----------------
// fps() returns selections in ASCENDING ORIGINAL-INDEX order (masked_select);
// rank-sort each run's indices before zipping along m (pairing matters).
// PRJ[0]=pe (ev-run pts @ Wpe), PRJ[1]=km (k-run pts @ Wk), PRJ[2]=vm (v-run @ Wv).
__global__ __launch_bounds__(256, 1) void finalize_kernel(
    const float* __restrict__ ev, const float* __restrict__ Wk,
    const float* __restrict__ Wv, const float* __restrict__ Wpe,
    const float* __restrict__ Wsa1, const float* __restrict__ Wsa2,
    const int* __restrict__ idx_ws, const float* __restrict__ partials,
    float* __restrict__ outvec_ws) {
  const int b = blockIdx.x;
  const int t = threadIdx.x;           // 256 threads = 4 waves
  const float* evb = ev + (size_t)b * N_ * C_;

  __shared__ float Wl[3][CN_][C_];        // 24 KB: Wpe, Wk, Wv
  __shared__ float W1l[CN_];
  __shared__ float W2l[C_][CN_ + 1];      // padded: conflict-free per-lane rows
  __shared__ int   lidx[3][M_], sidx[3][M_];
  __shared__ float XP[3][M_][C_];         // 24 KB selected rows
  __shared__ float PRJ[3][M_][CN_ + 1];   // padded
  __shared__ float sumx[C_], Pl[CN_], sl[M_], TP[4][CN_];

  // ---- stage weights ----
  {
    const float* Ws[3] = {Wpe, Wk, Wv};
#pragma unroll
    for (int r = 0; r < 3; ++r)
      for (int i = t; i < CN_ * C_ / 4; i += 256)
        ((float4*)&Wl[r][0][0])[i] = ((const float4*)Ws[r])[i];
    if (t < CN_) W1l[t] = Wsa1[t];
    for (int i = t; i < C_ * CN_; i += 256)
      W2l[i >> 6][i & 63] = Wsa2[i];      // scalar (padded dest not f4-aligned)
  }
  if (t < 192) {
    int r = t >> 6, mm = t & 63;
    lidx[r][mm] = idx_ws[(b * 3 + r) * M_ + mm];
  }
  if (t < C_) {
    float s = 0.f;
#pragma unroll
    for (int c = 0; c < NCHUNK; ++c) s += partials[((size_t)b * NCHUNK + c) * C_ + t];
    sumx[t] = s;
  }
  __syncthreads();
  if (t < 192) {       // parallel rank-sort: 3 runs × 64 slots
    int r = t >> 6, mm = t & 63;
    int my = lidx[r][mm];
    int rank = 0;
#pragma unroll
    for (int j = 0; j < M_; ++j)
      rank += (lidx[r][j] < my) || (lidx[r][j] == my && j < mm);
    sidx[r][rank] = my;
  }
  __syncthreads();
  // ---- stage selected rows: 192 rows × 8 quads ----
  for (int g = t; g < 3 * M_ * 8; g += 256) {
    int row = g >> 3, q = g & 7;
    int r = row >> 6, m = row & 63;
    int pi = sidx[r][m];
    *(float4*)&XP[r][m][q * 4] = ((const float4*)(evb + (size_t)pi * C_))[q];
  }
  __syncthreads();
  // ---- projections: wave r handles run r (lane = cn, W row in regs, x broadcast) ----
  {
    int w = t >> 6, cn = t & 63;
    if (w < 3) {
      float wr[C_];
#pragma unroll
      for (int q = 0; q < C_ / 4; ++q) {
        float4 v = *(const float4*)&Wl[w][cn][q * 4];
        wr[q * 4 + 0] = v.x; wr[q * 4 + 1] = v.y;
        wr[q * 4 + 2] = v.z; wr[q * 4 + 3] = v.w;
      }
      for (int m = 0; m < M_; ++m) {
        float a = 0.f;
#pragma unroll
        for (int q = 0; q < C_ / 4; ++q) {
          float4 x = *(const float4*)&XP[w][m][q * 4];   // wave-broadcast read
          a = fmaf(x.x, wr[q * 4 + 0], a);
          a = fmaf(x.y, wr[q * 4 + 1], a);
          a = fmaf(x.z, wr[q * 4 + 2], a);
          a = fmaf(x.w, wr[q * 4 + 3], a);
        }
        PRJ[w][m][cn] = a;
      }
    } else {
      // Pl[cn] = (Σ_n ev) @ Wpe^T
      float a = 0.f;
#pragma unroll
      for (int c = 0; c < C_; ++c) a = fmaf(sumx[c], Wl[0][cn][c], a);
      Pl[cn] = a;
    }
  }
  __syncthreads();
  // ---- logits + softmax: wave 0, lane m ----
  if (t < 64) {
    float cm = 0.f;
#pragma unroll 8
    for (int cn = 0; cn < CN_; ++cn)
      cm = fmaf(PRJ[1][t][cn] + PRJ[0][t][cn], W1l[cn], cm);
    float lg = -cm;
    float mx = lg;
#pragma unroll
    for (int off = 32; off; off >>= 1) mx = fmaxf(mx, __shfl_xor(mx, off));
    float e = expf(lg - mx);
    float ssum = e;
#pragma unroll
    for (int off = 32; off; off >>= 1) ssum += __shfl_xor(ssum, off);
    sl[t] = e / ssum;
  }
  __syncthreads();
  // ---- tvec partials: thread (cn = t&63, quarter h = t>>6) ----
  {
    int cn = t & 63, h = t >> 6;
    float a = 0.f;
#pragma unroll
    for (int i = 0; i < 16; ++i) {
      int mm = h * 16 + i;
      a = fmaf(sl[mm],
               fmaf((float)N_, PRJ[2][mm][cn], Pl[cn]) - (float)N_ * PRJ[0][mm][cn],
               a);
    }
    TP[h][cn] = a;
  }
  __syncthreads();
  if (t < C_) {
    float o = 0.f;
#pragma unroll 8
    for (int cn = 0; cn < CN_; ++cn) {
      float tv = TP[0][cn] + TP[1][cn] + TP[2][cn] + TP[3][cn];
      o = fmaf(tv, W2l[t][cn], o);
    }
    outvec_ws[b * C_ + t] = o;
  }
}

// ---------------- kernel 3: broadcast out[b][n][:] = outvec[b][:] ----------------
__global__ void bcast_kernel(const float* __restrict__ outvec_ws,
                             float4* __restrict__ out) {
  int i = blockIdx.x * 256 + threadIdx.x;   // < 4*4096*8
  int b = i >> 15;
  int j = i & 7;
  const float4* ov = (const float4*)outvec_ws;
  out[i] = ov[b * 8 + j];
}

extern "C" void kernel_launch(void* const* d_in, const int* in_sizes, int n_in,
                              void* d_out, int out_size, void* d_ws, size_t ws_size,
                              hipStream_t stream) {
  const float* ev   = (const float*)d_in[0];
  // d_in[1] = W_qs: provably unused (a_n cancels in softmax over m)
  const float* Wk   = (const float*)d_in[2];
  const float* Wv   = (const float*)d_in[3];
  const float* Wpe  = (const float*)d_in[4];
  const float* Wsa1 = (const float*)d_in[5];
  const float* Wsa2 = (const float*)d_in[6];
  float* out = (float*)d_out;

  char* ws = (char*)d_ws;
  int*   idx    = (int*)ws;                     // 12*64*4        = 3072 B
  float* parts  = (float*)(ws + 3072);          // 4*16*32*4      = 8192 B
  float* outvec = (float*)(ws + 11264);         // 4*32*4         = 512 B
  float* nrm    = (float*)(ws + 11776);         // 12*4096*4      = 196608 B
  float* zall   = (float*)(ws + 208384);        // 12*4096*32*4   = 6291456 B

  norms_kernel   <<<dim3(192), dim3(NTPB), 0, stream>>>(ev, Wk, Wv, nrm, zall, parts);
  fps_kernel     <<<dim3(12),  dim3(TPB),  0, stream>>>(ev, nrm, zall, parts, idx);
  finalize_kernel<<<dim3(4),   dim3(256),  0, stream>>>(ev, Wk, Wv, Wpe, Wsa1, Wsa2,
                                                        idx, parts, outvec);
  bcast_kernel   <<<dim3(512), dim3(256),  0, stream>>>(outvec, (float4*)out);
}

// Round 12
// 156.705 us; speedup vs baseline: 1.2427x; 1.0451x over previous
//
#include <hip/hip_runtime.h>

constexpr int N_ = 4096, C_ = 32, CN_ = 64, M_ = 64;
constexpr int TPB = 1024;             // fps block: 16 waves, 4/SIMD
constexpr int RPT = 3, LPT = 1;       // reg / LDS points per thread
constexpr int NREG = RPT * TPB;       // 3072
constexpr int NLDS = N_ - NREG;       // 1024
constexpr int NWAVES = TPB / 64;      // 16
constexpr int NTPB = 256;             // norms block
constexpr int NCHUNK = N_ / NTPB;     // 16

typedef float v2f  __attribute__((ext_vector_type(2)));
typedef float v16f __attribute__((ext_vector_type(16)));

// packed f32 FMA: acc.{lo,hi} += z.{lo,hi} * c.{lo,hi}; c is an SGPR pair
#define PKFMA(acc, zz, cc) \
  asm("v_pk_fma_f32 %0, %1, %2, %0" : "+v"(acc) : "v"(zz), "s"(cc))

// monotone f32 -> u32 map (total order preserved incl. negatives)
__device__ __forceinline__ unsigned fmap(float v) {
  unsigned u = __float_as_uint(v);
  u ^= (unsigned)((int)u >> 31) | 0x80000000u;
  return u;
}

// force a wave-uniform float into an SGPR
__device__ __forceinline__ float rfl(float v) {
  return __uint_as_float(__builtin_amdgcn_readfirstlane(__float_as_uint(v)));
}

// one DPP max-combine stage on a packed u64 key (VALU pipe — no LDS traffic).
template <int CTRL, int RM>
__device__ __forceinline__ unsigned long long kmax_dpp(unsigned long long k) {
  int lo = (int)(unsigned)k, hi = (int)(unsigned)(k >> 32);
  int plo = __builtin_amdgcn_update_dpp(lo, lo, CTRL, RM, 0xf, false);
  int phi = __builtin_amdgcn_update_dpp(hi, hi, CTRL, RM, 0xf, false);
  unsigned long long p =
      ((unsigned long long)(unsigned)phi << 32) | (unsigned)plo;
  return p > k ? p : k;
}

// full-wave max of packed key; lane 63 holds it.
__device__ __forceinline__ unsigned long long wave_kmax(unsigned long long k) {
  k = kmax_dpp<0x111, 0xF>(k);   // row_shr:1
  k = kmax_dpp<0x112, 0xF>(k);   // row_shr:2
  k = kmax_dpp<0x114, 0xF>(k);   // row_shr:4
  k = kmax_dpp<0x118, 0xF>(k);   // row_shr:8
  k = kmax_dpp<0x142, 0xA>(k);   // row_bcast:15 -> rows 1,3
  k = kmax_dpp<0x143, 0xC>(k);   // row_bcast:31 -> rows 2,3
  return k;
}

// ---------------- kernel 0: per-point z = G·x (f64 accum) + norms + Σx partials ----------------
// blk = (b*3+r)*16 + chunk ; r=0: G=I, r=1: G=Wk^T Wk, r=2: G=Wv^T Wv
__global__ __attribute__((amdgpu_flat_work_group_size(NTPB, NTPB),
                          amdgpu_waves_per_eu(1, 4)))
void norms_kernel(
    const float* __restrict__ ev, const float* __restrict__ Wk,
    const float* __restrict__ Wv, float* __restrict__ nrm_all,
    float* __restrict__ zall, float* __restrict__ partials) {
  int blk = blockIdx.x;
  int chunk = blk & (NCHUNK - 1), br = blk >> 4;
  int r = br % 3, b = br / 3;
  int t = threadIdx.x;
  __shared__ float G[C_][C_ + 1];
  const float* W = (r == 1) ? Wk : Wv;
  for (int e = t; e < C_ * C_; e += NTPB) {
    int a = e >> 5, d = e & 31;
    float g;
    if (r == 0) {
      g = (a == d) ? 1.f : 0.f;
    } else {
      double acc = 0.0;
      for (int q = 0; q < CN_; ++q)
        acc += (double)W[q * C_ + a] * (double)W[q * C_ + d];
      g = (float)acc;
    }
    G[a][d] = g;
  }
  __syncthreads();
  int p = chunk * NTPB + t;
  const float4* row = (const float4*)(ev + ((size_t)b * N_ + p) * C_);
  float x[C_];
#pragma unroll
  for (int q = 0; q < C_ / 4; ++q) {
    float4 v = row[q];
    x[q * 4 + 0] = v.x; x[q * 4 + 1] = v.y; x[q * 4 + 2] = v.z; x[q * 4 + 3] = v.w;
  }
  double n = 0.0;
  float z[C_];
#pragma unroll
  for (int a = 0; a < C_; ++a) {
    double ta = 0.0;
#pragma unroll
    for (int d = 0; d < C_; ++d) ta += (double)G[a][d] * (double)x[d];
    z[a] = (float)ta;
    n += ta * (double)x[a];
  }
  nrm_all[(size_t)br * N_ + p] = (float)n;
  float4* zrow = (float4*)(zall + ((size_t)br * N_ + p) * C_);
#pragma unroll
  for (int q = 0; q < C_ / 4; ++q)
    zrow[q] = make_float4(z[q * 4 + 0], z[q * 4 + 1], z[q * 4 + 2], z[q * 4 + 3]);

  if (r == 0) {   // deterministic per-chunk Σx partials (no atomics)
    __shared__ float msum[NTPB / 64][C_];
#pragma unroll
    for (int d = 0; d < C_; ++d) {
      float s = x[d];
#pragma unroll
      for (int off = 32; off; off >>= 1) s += __shfl_xor(s, off);
      if ((t & 63) == 0) msum[t >> 6][d] = s;
    }
    __syncthreads();
    if (t < C_)
      partials[((size_t)b * NCHUNK + chunk) * C_ + t] =
          msum[0][t] + msum[1][t] + msum[2][t] + msum[3][t];
  }
}

// ---------------- kernel 1: FPS — one block per (batch,run), z-metric ----------------
// d(i, sel) = n_i - 2 * z_i · x_sel + n_sel    (G symmetric: x_i·G·c = z_i·c)
__global__ __attribute__((amdgpu_flat_work_group_size(TPB, TPB),
                          amdgpu_waves_per_eu(4, 4)))
void fps_kernel(
    const float* __restrict__ ev, const float* __restrict__ nrm_all,
    const float* __restrict__ zall, const float* __restrict__ partials,
    int* __restrict__ idx_ws) {
  const int t = threadIdx.x;
  const int blk = blockIdx.x;          // b*3 + r
  const int b = blk / 3;
  const float* evb = ev + (size_t)b * N_ * C_;
  const float* nrm = nrm_all + (size_t)blk * N_;
  const float4* zb4 = (const float4*)(zall + (size_t)blk * N_ * C_);

  __shared__ float LP[C_ / 4][NLDS][4];   // [q][col][4] — conflict-free b128 (128 KB)
  __shared__ float cf0[C_];               // barycenter (round 0 only)
  __shared__ unsigned long long redK[2][NWAVES];

  v2f z2[RPT][C_ / 2];
  float pn[RPT], dmin[RPT];
  float nl, dminL;

  // ---- load reg z-points (as VGPR pairs for v_pk_fma_f32) ----
#pragma unroll
  for (int j = 0; j < RPT; ++j) {
    int p = j * TPB + t;
#pragma unroll
    for (int q = 0; q < C_ / 4; ++q) {
      float4 v = zb4[(size_t)p * 8 + q];
      z2[j][2 * q + 0] = v2f{v.x, v.y};
      z2[j][2 * q + 1] = v2f{v.z, v.w};
    }
    pn[j] = nrm[p];
    dmin[j] = 1e10f;
  }
  // ---- stage LDS z-point (1 per thread), [q][col] layout ----
  {
    int p = NREG + t;
#pragma unroll
    for (int q = 0; q < C_ / 4; ++q) {
      float4 v = zb4[(size_t)p * 8 + q];
      *(float4*)&LP[q][t][0] = v;
    }
    nl = nrm[p];
    dminL = 1e10f;
  }
  // ---- barycenter from partials (deterministic) ----
  if (t < C_) {
    float s = 0.f;
#pragma unroll
    for (int c = 0; c < NCHUNK; ++c) s += partials[((size_t)b * NCHUNK + c) * C_ + t];
    cf0[t] = s * (1.f / (float)N_);
  }
  __syncthreads();   // LP + cf0 ready

  // csp[] pairs are SGPR-resident. Returns wave-reduced packed key
  // (fmap(best_v) << 12) | (4095 - best_idx) via DPP (no LDS ops).
  auto eval = [&](const v2f (&csp)[C_ / 2], float curN,
                  bool update) -> unsigned long long {
    v2f a0 = {0.f, 0.f}, a1 = {0.f, 0.f}, a2 = {0.f, 0.f}, aL = {0.f, 0.f};
#pragma unroll
    for (int q = 0; q < C_ / 4; ++q) {
      float4 l = *(const float4*)&LP[q][t][0];
      v2f l0 = {l.x, l.y}, l1 = {l.z, l.w};
      PKFMA(a0, z2[0][2 * q + 0], csp[2 * q + 0]);
      PKFMA(a0, z2[0][2 * q + 1], csp[2 * q + 1]);
      PKFMA(a1, z2[1][2 * q + 0], csp[2 * q + 0]);
      PKFMA(a1, z2[1][2 * q + 1], csp[2 * q + 1]);
      PKFMA(a2, z2[2][2 * q + 0], csp[2 * q + 0]);
      PKFMA(a2, z2[2][2 * q + 1], csp[2 * q + 1]);
      PKFMA(aL, l0, csp[2 * q + 0]);
      PKFMA(aL, l1, csp[2 * q + 1]);
    }
    float acc[RPT] = {a0.x + a0.y, a1.x + a1.y, a2.x + a2.y};
    float bv = -3e38f; int bi = 0;
#pragma unroll
    for (int j = 0; j < RPT; ++j) {
      float d = fmaf(-2.f, acc[j], pn[j]) + curN;
      float v;
      if (update) { dmin[j] = fminf(dmin[j], d); v = dmin[j]; }
      else v = d;
      if (v > bv) { bv = v; bi = j * TPB + t; }   // strict > keeps lowest index
    }
    {
      float d = fmaf(-2.f, aL.x + aL.y, nl) + curN;
      float v;
      if (update) { dminL = fminf(dminL, d); v = dminL; }
      else v = d;
      if (v > bv) { bv = v; bi = NREG + t; }
    }
    unsigned long long k =
        ((unsigned long long)fmap(bv) << 12) | (unsigned)(4095 - bi);
    return wave_kmax(k);
  };

  // ---- round 0: barycenter (additive shift irrelevant for argmax; no dmin update) ----
  {
    v2f csp[C_ / 2];
#pragma unroll
    for (int i = 0; i < C_ / 2; ++i)
      csp[i] = v2f{rfl(cf0[2 * i]), rfl(cf0[2 * i + 1])};
    unsigned long long k = eval(csp, 0.f, false);
    if ((t & 63) == 63) redK[0][t >> 6] = k;
  }
  __syncthreads();

  // ---- main loop: 1 barrier/iter; cross-wave reduce = 1 ds_read_b64 +
  // 4 DPP stages + readlane; centroid row fetched on the SCALAR pipe ----
  for (int it = 0; it < M_; ++it) {
    int rb = it & 1;
    unsigned long long k = redK[rb][t & (NWAVES - 1)];
    k = kmax_dpp<0x111, 0xF>(k);
    k = kmax_dpp<0x112, 0xF>(k);
    k = kmax_dpp<0x114, 0xF>(k);
    k = kmax_dpp<0x118, 0xF>(k);
    unsigned klo = (unsigned)__builtin_amdgcn_readlane((int)(unsigned)k, 15);
    int jsel = 4095 - (int)(klo & 4095u);          // SGPR-uniform
    if (t == 0) idx_ws[blk * M_ + it] = jsel;
    // owner kills its dmin slot (never re-select) — static indices only
    if (jsel < NREG) {
      if ((jsel & (TPB - 1)) == t) {
        int j = jsel >> 10;
        if (j == 0) dmin[0] = -3e38f;
        else if (j == 1) dmin[1] = -3e38f;
        else dmin[2] = -3e38f;
      }
    } else {
      if (jsel - NREG == t) dminL = -3e38f;
    }
    if (it == M_ - 1) break;
    // scalar-pipe fetch of the selected point's 128B row + norm (uniform addr)
    const float* cfp = evb + (size_t)jsel * C_;
    const float* nrmp = nrm + jsel;
    v16f cs0, cs1; float curN;
    asm volatile(
        "s_load_dwordx16 %0, %3, 0\n\t"
        "s_load_dwordx16 %1, %3, 64\n\t"
        "s_load_dword %2, %4, 0\n\t"
        "s_waitcnt lgkmcnt(0)"
        : "=&s"(cs0), "=&s"(cs1), "=&s"(curN)
        : "s"(cfp), "s"(nrmp));
    v2f csp[C_ / 2];
#pragma unroll
    for (int i = 0; i < 8; ++i) {
      csp[i]     = v2f{cs0[2 * i], cs0[2 * i + 1]};
      csp[8 + i] = v2f{cs1[2 * i], cs1[2 * i + 1]};
    }
    unsigned long long kk = eval(csp, curN, true);
    if ((t & 63) == 63) redK[rb ^ 1][t >> 6] = kk;
    __syncthreads();
  }
}

// ---------------- kernel 2: finalize (256 threads per batch) ----------------
// fps() returns selections in ASCENDING ORIGINAL-INDEX order (masked_select);
// rank-sort each run's indices before zipping along m (pairing matters).
// PRJ[0]=pe (ev-run pts @ Wpe), PRJ[1]=km (k-run pts @ Wk), PRJ[2]=vm (v-run @ Wv).
__global__ __launch_bounds__(256, 1) void finalize_kernel(
    const float* __restrict__ ev, const float* __restrict__ Wk,
    const float* __restrict__ Wv, const float* __restrict__ Wpe,
    const float* __restrict__ Wsa1, const float* __restrict__ Wsa2,
    const int* __restrict__ idx_ws, const float* __restrict__ partials,
    float* __restrict__ outvec_ws) {
  const int b = blockIdx.x;
  const int t = threadIdx.x;           // 256 threads = 4 waves
  const float* evb = ev + (size_t)b * N_ * C_;

  __shared__ float Wl[3][CN_][C_];        // 24 KB: Wpe, Wk, Wv
  __shared__ float W1l[CN_];
  __shared__ float W2l[C_][CN_ + 1];      // padded: conflict-free per-lane rows
  __shared__ int   lidx[3][M_], sidx[3][M_];
  __shared__ float XP[3][M_][C_];         // 24 KB selected rows
  __shared__ float PRJ[3][M_][CN_ + 1];   // padded
  __shared__ float sumx[C_], Pl[CN_], sl[M_], TP[4][CN_];

  // ---- stage weights ----
  {
    const float* Ws[3] = {Wpe, Wk, Wv};
#pragma unroll
    for (int r = 0; r < 3; ++r)
      for (int i = t; i < CN_ * C_ / 4; i += 256)
        ((float4*)&Wl[r][0][0])[i] = ((const float4*)Ws[r])[i];
    if (t < CN_) W1l[t] = Wsa1[t];
    for (int i = t; i < C_ * CN_; i += 256)
      W2l[i >> 6][i & 63] = Wsa2[i];      // scalar (padded dest not f4-aligned)
  }
  if (t < 192) {
    int r = t >> 6, mm = t & 63;
    lidx[r][mm] = idx_ws[(b * 3 + r) * M_ + mm];
  }
  if (t < C_) {
    float s = 0.f;
#pragma unroll
    for (int c = 0; c < NCHUNK; ++c) s += partials[((size_t)b * NCHUNK + c) * C_ + t];
    sumx[t] = s;
  }
  __syncthreads();
  if (t < 192) {       // parallel rank-sort: 3 runs × 64 slots
    int r = t >> 6, mm = t & 63;
    int my = lidx[r][mm];
    int rank = 0;
#pragma unroll
    for (int j = 0; j < M_; ++j)
      rank += (lidx[r][j] < my) || (lidx[r][j] == my && j < mm);
    sidx[r][rank] = my;
  }
  __syncthreads();
  // ---- stage selected rows: 192 rows × 8 quads ----
  for (int g = t; g < 3 * M_ * 8; g += 256) {
    int row = g >> 3, q = g & 7;
    int r = row >> 6, m = row & 63;
    int pi = sidx[r][m];
    *(float4*)&XP[r][m][q * 4] = ((const float4*)(evb + (size_t)pi * C_))[q];
  }
  __syncthreads();
  // ---- projections: wave r handles run r (lane = cn, W row in regs, x broadcast) ----
  {
    int w = t >> 6, cn = t & 63;
    if (w < 3) {
      float wr[C_];
#pragma unroll
      for (int q = 0; q < C_ / 4; ++q) {
        float4 v = *(const float4*)&Wl[w][cn][q * 4];
        wr[q * 4 + 0] = v.x; wr[q * 4 + 1] = v.y;
        wr[q * 4 + 2] = v.z; wr[q * 4 + 3] = v.w;
      }
      for (int m = 0; m < M_; ++m) {
        float a = 0.f;
#pragma unroll
        for (int q = 0; q < C_ / 4; ++q) {
          float4 x = *(const float4*)&XP[w][m][q * 4];   // wave-broadcast read
          a = fmaf(x.x, wr[q * 4 + 0], a);
          a = fmaf(x.y, wr[q * 4 + 1], a);
          a = fmaf(x.z, wr[q * 4 + 2], a);
          a = fmaf(x.w, wr[q * 4 + 3], a);
        }
        PRJ[w][m][cn] = a;
      }
    } else {
      // Pl[cn] = (Σ_n ev) @ Wpe^T
      float a = 0.f;
#pragma unroll
      for (int c = 0; c < C_; ++c) a = fmaf(sumx[c], Wl[0][cn][c], a);
      Pl[cn] = a;
    }
  }
  __syncthreads();
  // ---- logits + softmax: wave 0, lane m ----
  if (t < 64) {
    float cm = 0.f;
#pragma unroll 8
    for (int cn = 0; cn < CN_; ++cn)
      cm = fmaf(PRJ[1][t][cn] + PRJ[0][t][cn], W1l[cn], cm);
    float lg = -cm;
    float mx = lg;
#pragma unroll
    for (int off = 32; off; off >>= 1) mx = fmaxf(mx, __shfl_xor(mx, off));
    float e = expf(lg - mx);
    float ssum = e;
#pragma unroll
    for (int off = 32; off; off >>= 1) ssum += __shfl_xor(ssum, off);
    sl[t] = e / ssum;
  }
  __syncthreads();
  // ---- tvec partials: thread (cn = t&63, quarter h = t>>6) ----
  {
    int cn = t & 63, h = t >> 6;
    float a = 0.f;
#pragma unroll
    for (int i = 0; i < 16; ++i) {
      int mm = h * 16 + i;
      a = fmaf(sl[mm],
               fmaf((float)N_, PRJ[2][mm][cn], Pl[cn]) - (float)N_ * PRJ[0][mm][cn],
               a);
    }
    TP[h][cn] = a;
  }
  __syncthreads();
  if (t < C_) {
    float o = 0.f;
#pragma unroll 8
    for (int cn = 0; cn < CN_; ++cn) {
      float tv = TP[0][cn] + TP[1][cn] + TP[2][cn] + TP[3][cn];
      o = fmaf(tv, W2l[t][cn], o);
    }
    outvec_ws[b * C_ + t] = o;
  }
}

// ---------------- kernel 3: broadcast out[b][n][:] = outvec[b][:] ----------------
__global__ void bcast_kernel(const float* __restrict__ outvec_ws,
                             float4* __restrict__ out) {
  int i = blockIdx.x * 256 + threadIdx.x;   // < 4*4096*8
  int b = i >> 15;
  int j = i & 7;
  const float4* ov = (const float4*)outvec_ws;
  out[i] = ov[b * 8 + j];
}

extern "C" void kernel_launch(void* const* d_in, const int* in_sizes, int n_in,
                              void* d_out, int out_size, void* d_ws, size_t ws_size,
                              hipStream_t stream) {
  const float* ev   = (const float*)d_in[0];
  // d_in[1] = W_qs: provably unused (a_n cancels in softmax over m)
  const float* Wk   = (const float*)d_in[2];
  const float* Wv   = (const float*)d_in[3];
  const float* Wpe  = (const float*)d_in[4];
  const float* Wsa1 = (const float*)d_in[5];
  const float* Wsa2 = (const float*)d_in[6];
  float* out = (float*)d_out;

  char* ws = (char*)d_ws;
  int*   idx    = (int*)ws;                     // 12*64*4        = 3072 B
  float* parts  = (float*)(ws + 3072);          // 4*16*32*4      = 8192 B
  float* outvec = (float*)(ws + 11264);         // 4*32*4         = 512 B
  float* nrm    = (float*)(ws + 11776);         // 12*4096*4      = 196608 B
  float* zall   = (float*)(ws + 208384);        // 12*4096*32*4   = 6291456 B

  norms_kernel   <<<dim3(192), dim3(NTPB), 0, stream>>>(ev, Wk, Wv, nrm, zall, parts);
  fps_kernel     <<<dim3(12),  dim3(TPB),  0, stream>>>(ev, nrm, zall, parts, idx);
  finalize_kernel<<<dim3(4),   dim3(256),  0, stream>>>(ev, Wk, Wv, Wpe, Wsa1, Wsa2,
                                                        idx, parts, outvec);
  bcast_kernel   <<<dim3(512), dim3(256),  0, stream>>>(outvec, (float4*)out);
}